// Round 8
// baseline (87870.776 us; speedup 1.0000x reference)
//
#include <hip/hip_runtime.h>
#include <math.h>

#define T_STEPS 16384
#define IN 512
#define HID 1024
#define NC 512
#define NWG 64
#define TPB 512
#define TB 32           // t-rows per block in dense kernel
typedef unsigned long long ull;

__device__ __forceinline__ float sigmoidf_(float x) { return 1.f / (1.f + expf(-x)); }

// ---------------- Kernel 0: seed epoch-tagged h buffer ----------------
// bufp[p][j] = {epoch:u32 | h:f32}. h_t carries epoch t+2, parity (t+1)&1;
// h0 -> epoch 1, parity 0. ws is NOT re-poisoned between replays -> reset both.
__global__ void init_k(const float* __restrict__ h0, ull* __restrict__ bufp)
{
    const int j = threadIdx.x;  // 1024 threads, 1 block
    bufp[j]       = (1ull << 32) | (ull)__float_as_uint(h0[j]);
    bufp[HID + j] = 0ull;
}

// ---------------- Kernel 1: persistent LSTM recurrence ----------------
// 64 WGs x 512 threads (8 waves). WG wg owns h elems [wg*16, wg*16+16);
// wave wv owns elems je0=wg*16+wv*2 +{0,1} and their 8 gate rows (4 gates x 2).
// Weights in VGPRs (192 floats/lane). Poll: thread stages fused words
// {tid*2, tid*2+1} into LDS; stale-selective reload; __syncthreads_and detect.
// ROUND 8 A/B: publish via atomic swap RMW (executes AT the MALL -> promptly
// visible cross-XCD) instead of a relaxed store. Only change vs round 7.
__global__ __launch_bounds__(TPB, 2) void lstm_rec(
    const float* __restrict__ X,     // [T, IN]
    const float* __restrict__ c0,    // [HID]
    const float* __restrict__ W_ih,  // [4H, IN]
    const float* __restrict__ W_hh,  // [4H, HID]
    const float* __restrict__ b_ih,  // [4H]
    const float* __restrict__ b_hh,  // [4H]
    float* __restrict__ h_all,       // ws [T, HID]
    ull* __restrict__ bufp)          // ws [2][HID] epoch|h
{
    __shared__ float svh[HID];

    const int tid  = threadIdx.x;
    const int wg   = blockIdx.x;
    const int lane = tid & 63;
    const int wv   = tid >> 6;          // 0..7
    const int je0  = wg * 16 + wv * 2;  // wave's first h element
    const int kb   = lane * 4;

    // --- weights for 8 rows (r = q*2+e): row = q*HID + je0+e ---
    float4 w[8][6];
    float bias[8];
    #pragma unroll
    for (int q = 0; q < 4; ++q) {
        #pragma unroll
        for (int e = 0; e < 2; ++e) {
            const int r = q * 2 + e;
            const int row = q * HID + je0 + e;
            #pragma unroll
            for (int c = 0; c < 6; ++c) {
                const int k = kb + c * 256;
                w[r][c] = (k < IN)
                    ? *(const float4*)&W_ih[(size_t)row * IN + k]
                    : *(const float4*)&W_hh[(size_t)row * HID + (k - IN)];
            }
            bias[r] = b_ih[row] + b_hh[row];
        }
    }
    // lane 0 tracks elem je0, lanes>=1 track elem je0+1 (only lanes 0,1 store)
    const int esel = (lane == 0) ? 0 : 1;
    float c_state = c0[je0 + esel];
    bool dead = false;
    __syncthreads();

    for (int t = 0; t < T_STEPS; ++t) {
        const int p = t & 1;
        const unsigned want = (unsigned)(t + 1);

        // x slice to registers (issued before the poll: latency overlap)
        const float* xr = X + (size_t)t * IN;
        const float4 x0 = *(const float4*)&xr[kb];
        const float4 x1 = *(const float4*)&xr[kb + 256];

        // ---- poll: thread owns fused words tid*2, tid*2+1 (16B coalesced) ----
        ull* src = bufp + (size_t)p * HID;
        const int i0 = tid * 2;
        ull v0 = __hip_atomic_load(&src[i0],     __ATOMIC_RELAXED, __HIP_MEMORY_SCOPE_AGENT);
        ull v1 = __hip_atomic_load(&src[i0 + 1], __ATOMIC_RELAXED, __HIP_MEMORY_SCOPE_AGENT);
        unsigned spn = 0;
        int ok;
        do {
            if ((unsigned)(v0 >> 32) < want)
                v0 = __hip_atomic_load(&src[i0],     __ATOMIC_RELAXED, __HIP_MEMORY_SCOPE_AGENT);
            if ((unsigned)(v1 >> 32) < want)
                v1 = __hip_atomic_load(&src[i0 + 1], __ATOMIC_RELAXED, __HIP_MEMORY_SCOPE_AGENT);
            const bool fresh = ((unsigned)(v0 >> 32) >= want) & ((unsigned)(v1 >> 32) >= want);
            svh[i0]     = __uint_as_float((unsigned)v0);
            svh[i0 + 1] = __uint_as_float((unsigned)v1);
            const int timeout = (++spn > 2000000u);   // fail, don't hang
            ok = __syncthreads_and((int)fresh | timeout | (int)dead);
        } while (!ok);
        if (spn > 2000000u) dead = true;

        // ---- read h slice from LDS, then release svh for next step ----
        const float4 s0 = *(const float4*)&svh[kb];
        const float4 s1 = *(const float4*)&svh[kb + 256];
        const float4 s2 = *(const float4*)&svh[kb + 512];
        const float4 s3 = *(const float4*)&svh[kb + 768];
        __syncthreads();

        // ---- GEMV: 8 rows x 24 elems/lane, weights in regs ----
        float acc[8];
        #pragma unroll
        for (int r = 0; r < 8; ++r) {
            acc[r] = w[r][0].x*x0.x + w[r][0].y*x0.y + w[r][0].z*x0.z + w[r][0].w*x0.w
                   + w[r][1].x*x1.x + w[r][1].y*x1.y + w[r][1].z*x1.z + w[r][1].w*x1.w
                   + w[r][2].x*s0.x + w[r][2].y*s0.y + w[r][2].z*s0.z + w[r][2].w*s0.w
                   + w[r][3].x*s1.x + w[r][3].y*s1.y + w[r][3].z*s1.z + w[r][3].w*s1.w
                   + w[r][4].x*s2.x + w[r][4].y*s2.y + w[r][4].z*s2.z + w[r][4].w*s2.w
                   + w[r][5].x*s3.x + w[r][5].y*s3.y + w[r][5].z*s3.z + w[r][5].w*s3.w;
        }
        // full butterfly: every lane ends with all 8 row sums
        #pragma unroll
        for (int r = 0; r < 8; ++r) {
            float s = acc[r];
            #pragma unroll
            for (int off = 32; off; off >>= 1) s += __shfl_xor(s, off);
            acc[r] = s;
        }

        // constant-index selects (no runtime array indexing -> no scratch)
        const float gi = (esel == 0) ? acc[0] + bias[0] : acc[1] + bias[1];
        const float gf = (esel == 0) ? acc[2] + bias[2] : acc[3] + bias[3];
        const float gg = (esel == 0) ? acc[4] + bias[4] : acc[5] + bias[5];
        const float go = (esel == 0) ? acc[6] + bias[6] : acc[7] + bias[7];
        const float iv = sigmoidf_(gi);
        const float fv = sigmoidf_(gf);
        const float gv = tanhf(gg);
        const float ov = sigmoidf_(go);
        c_state = fv * c_state + iv * gv;
        const float h = ov * tanhf(c_state);

        if (lane < 2) {
            const int j = je0 + lane;
            // publish via RMW: executes at the MALL atomic unit -> immediate
            // cross-XCD visibility (vs relaxed store possibly lingering in
            // write buffers). h_all (non-critical) after.
            (void)__hip_atomic_exchange(&bufp[(size_t)(p ^ 1) * HID + j],
                ((ull)(unsigned)(t + 2) << 32) | (ull)__float_as_uint(h),
                __ATOMIC_RELAXED, __HIP_MEMORY_SCOPE_AGENT);
            h_all[(size_t)t * HID + j] = h;
        }
    }
}

// ---------------- Kernel 2: out_t = softmax_C(h_t @ Wd^T + bd) ----------------
__global__ __launch_bounds__(256, 2) void dense_softmax(
    const float* __restrict__ h_all, const float* __restrict__ Wd,
    const float* __restrict__ bd, float* __restrict__ P)
{
    __shared__ float buf[TB * NC];    // 64KB union: hs[TB][128] then ls[TB][NC]
    const int tid = threadIdx.x;
    const int t0  = blockIdx.x * TB;
    const int c0 = tid, c1 = tid + 256;

    float acc0[TB], acc1[TB];
    #pragma unroll
    for (int r = 0; r < TB; ++r) { acc0[r] = 0.f; acc1[r] = 0.f; }

    const float4* wrow0 = (const float4*)&Wd[(size_t)c0 * HID];
    const float4* wrow1 = (const float4*)&Wd[(size_t)c1 * HID];

    for (int kc = 0; kc < HID / 128; ++kc) {
        #pragma unroll
        for (int i = 0; i < 4; ++i) {
            const int idx4 = tid + i * 256;
            const int r = idx4 >> 5, kk = (idx4 & 31) * 4;
            *(float4*)&buf[r * 128 + kk] =
                *(const float4*)&h_all[(size_t)(t0 + r) * HID + kc * 128 + kk];
        }
        __syncthreads();
        #pragma unroll 8
        for (int k4 = 0; k4 < 32; ++k4) {
            const float4 a = wrow0[kc * 32 + k4];
            const float4 b = wrow1[kc * 32 + k4];
            #pragma unroll
            for (int r = 0; r < TB; ++r) {
                const float4 h4 = *(const float4*)&buf[r * 128 + k4 * 4];
                acc0[r] += a.x*h4.x + a.y*h4.y + a.z*h4.z + a.w*h4.w;
                acc1[r] += b.x*h4.x + b.y*h4.y + b.z*h4.z + b.w*h4.w;
            }
        }
        __syncthreads();
    }

    const float bb0 = bd[c0], bb1 = bd[c1];
    #pragma unroll
    for (int r = 0; r < TB; ++r) {
        buf[r * NC + c0] = acc0[r] + bb0;
        buf[r * NC + c1] = acc1[r] + bb1;
    }
    __syncthreads();

    const int lane = tid & 63, wvv = tid >> 6;
    for (int rr = 0; rr < 8; ++rr) {
        const int r = wvv * 8 + rr;
        float vals[8];
        float m = -1e30f;
        #pragma unroll
        for (int jx = 0; jx < 8; ++jx) { vals[jx] = buf[r * NC + lane + 64 * jx]; m = fmaxf(m, vals[jx]); }
        #pragma unroll
        for (int off = 32; off; off >>= 1) m = fmaxf(m, __shfl_xor(m, off));
        float s = 0.f;
        #pragma unroll
        for (int jx = 0; jx < 8; ++jx) { vals[jx] = expf(vals[jx] - m); s += vals[jx]; }
        #pragma unroll
        for (int off = 32; off; off >>= 1) s += __shfl_xor(s, off);
        const float inv = 1.f / s;
        #pragma unroll
        for (int jx = 0; jx < 8; ++jx)
            P[(size_t)(t0 + r) * NC + lane + 64 * jx] = vals[jx] * inv;
    }
}

// ---------------- Kernel 3a: colsum[c] = sum_t exp(P[t][c]) ----------------
__global__ __launch_bounds__(256) void colsum_k(const float* __restrict__ P, float* __restrict__ cs)
{
    const int tid = threadIdx.x;
    const int c  = blockIdx.x * 16 + (tid & 15);
    const int tr = tid >> 4;
    float s = 0.f;
    #pragma unroll 8
    for (int t = tr; t < T_STEPS; t += 16) s += expf(P[(size_t)t * NC + c]);
    __shared__ float red[256];
    red[tid] = s; __syncthreads();
    for (int off = 128; off >= 16; off >>= 1) {
        if (tid < off) red[tid] += red[tid + off];
        __syncthreads();
    }
    if (tid < 16) cs[blockIdx.x * 16 + tid] = red[tid];
}

// ---------------- Kernel 3b: out = exp(P) / colsum ----------------
__global__ __launch_bounds__(256) void norm_k(float* P, const float* __restrict__ cs)
{
    size_t i = (size_t)blockIdx.x * 256 + threadIdx.x;
    const size_t n = (size_t)T_STEPS * NC;
    const size_t stride = (size_t)gridDim.x * 256;
    for (; i < n; i += stride) P[i] = expf(P[i]) / cs[i & (NC - 1)];
}

extern "C" void kernel_launch(void* const* d_in, const int* in_sizes, int n_in,
                              void* d_out, int out_size, void* d_ws, size_t ws_size,
                              hipStream_t stream) {
    const float* X    = (const float*)d_in[0];
    const float* h0   = (const float*)d_in[1];
    const float* c0   = (const float*)d_in[2];
    const float* W_ih = (const float*)d_in[3];
    const float* W_hh = (const float*)d_in[4];
    const float* b_ih = (const float*)d_in[5];
    const float* b_hh = (const float*)d_in[6];
    const float* Wd   = (const float*)d_in[7];
    const float* bd   = (const float*)d_in[8];
    float* out = (float*)d_out;

    char* ws = (char*)d_ws;
    ull*   bufp  = (ull*)ws;                     // [2][HID] epoch|h
    float* cs    = (float*)(ws + 16384);         // [NC]
    float* h_all = (float*)(ws + 32768);         // [T, HID]

    init_k<<<1, HID, 0, stream>>>(h0, bufp);
    lstm_rec<<<NWG, TPB, 0, stream>>>(X, c0, W_ih, W_hh, b_ih, b_hh, h_all, bufp);
    dense_softmax<<<T_STEPS / TB, 256, 0, stream>>>(h_all, Wd, bd, out);
    colsum_k<<<NC / 16, 256, 0, stream>>>(out, cs);
    norm_k<<<2048, 256, 0, stream>>>(out, cs);
}

// Round 9
// 78548.615 us; speedup vs baseline: 1.1187x; 1.1187x over previous
//
#include <hip/hip_runtime.h>
#include <math.h>

#define T_STEPS 16384
#define IN 512
#define HID 1024
#define NC 512
#define NWG 256
#define TPB 256
typedef unsigned long long ull;

__device__ __forceinline__ float sigmoidf_(float x) { return 1.f / (1.f + expf(-x)); }

// ---------------- Kernel 0: seed epoch-tagged h buffer ----------------
// bufp[p][j] = {epoch:u32 | h:f32}. Step t publishes epoch t+2 at parity
// (t+1)&1; step t polls epoch t+1 at parity t&1. h0 -> epoch 1, parity 0.
// ws is NOT re-poisoned between replays -> reset both parities every launch.
__global__ void init_k(const float* __restrict__ h0, ull* __restrict__ bufp)
{
    const int j = threadIdx.x;  // 1024 threads, 1 block
    bufp[j]       = (1ull << 32) | (ull)__float_as_uint(h0[j]);
    bufp[HID + j] = 0ull;
}

// ---------------- Kernel 1: persistent LSTM recurrence + fused dense ----------------
// 256 WGs x 256 threads (4 waves), 1 WG/CU. Wave wv owns h elem j=wg*4+wv and
// its 4 gate rows (weights in regs/AGPRs). Poll: thread stages 4 fused words
// into double-buffered svh; stale-selective reload; __syncthreads_and detect.
// NEW: waves 0,1 compute this WG's 2 rows of logits[t-1] = h_{t-1}.Wd^T + bd
// during the wait window (after publish) -> absorbs the 69-GFLOP tail GEMM
// into otherwise-idle latency time and keeps the VALU (and clocks) busy.
__global__ __launch_bounds__(TPB, 1) void lstm_rec(
    const float* __restrict__ X,     // [T, IN]
    const float* __restrict__ c0,    // [HID]
    const float* __restrict__ W_ih,  // [4H, IN]
    const float* __restrict__ W_hh,  // [4H, HID]
    const float* __restrict__ b_ih,  // [4H]
    const float* __restrict__ b_hh,  // [4H]
    const float* __restrict__ Wd,    // [NC, HID]
    const float* __restrict__ bd,    // [NC]
    float* __restrict__ logits,      // ws [T, NC]
    ull* __restrict__ bufp)          // ws [2][HID] epoch|h
{
    __shared__ float svh[2][HID];    // double-buffered staged h

    const int tid  = threadIdx.x;
    const int wg   = blockIdx.x;
    const int lane = tid & 63;
    const int wv   = tid >> 6;
    const int j    = wg * 4 + wv;    // owned h element
    const int kb   = lane * 4;

    // --- gate weights for the 4 rows of elem j: lane covers k=kb+c*256 ---
    float4 w[4][6];
    float bias[4];
    #pragma unroll
    for (int q = 0; q < 4; ++q) {
        const int row = q * HID + j;
        #pragma unroll
        for (int c = 0; c < 6; ++c) {
            const int k = kb + c * 256;
            w[q][c] = (k < IN)
                ? *(const float4*)&W_ih[(size_t)row * IN + k]
                : *(const float4*)&W_hh[(size_t)row * HID + (k - IN)];
        }
        bias[q] = b_ih[row] + b_hh[row];
    }

    // --- dense weights: wave wv<2 owns C-row wg*2+wv (16 floats/lane) ---
    const int drow = wg * 2 + wv;
    float4 wd[4];
    float dbias = 0.f;
    if (wv < 2) {
        #pragma unroll
        for (int c = 0; c < 4; ++c)
            wd[c] = *(const float4*)&Wd[(size_t)drow * HID + kb + c * 256];
        dbias = bd[drow];
    }

    float c_state = c0[j];
    bool dead = false;

    // one extra pseudo-step (t == T_STEPS) computes logits[T-1] only
    for (int t = 0; t <= T_STEPS; ++t) {
        const int p = t & 1;
        const unsigned want = (unsigned)(t + 1);

        float4 x0, x1;
        if (t < T_STEPS) {   // x prefetch (overlaps the poll)
            const float* xr = X + (size_t)t * IN;
            x0 = *(const float4*)&xr[kb];
            x1 = *(const float4*)&xr[kb + 256];
        }

        // ---- poll h_{t-1}: fused epoch|data words, stale-selective reload ----
        ull* src = bufp + (size_t)p * HID;
        ull v[4];
        #pragma unroll
        for (int c = 0; c < 4; ++c)
            v[c] = __hip_atomic_load(&src[tid + 256 * c],
                                     __ATOMIC_RELAXED, __HIP_MEMORY_SCOPE_AGENT);
        unsigned spn = 0;
        int ok;
        do {
            bool all = true;
            #pragma unroll
            for (int c = 0; c < 4; ++c) {
                if ((unsigned)(v[c] >> 32) < want)
                    v[c] = __hip_atomic_load(&src[tid + 256 * c],
                                             __ATOMIC_RELAXED, __HIP_MEMORY_SCOPE_AGENT);
                all &= ((unsigned)(v[c] >> 32) >= want);
            }
            #pragma unroll
            for (int c = 0; c < 4; ++c)
                svh[p][tid + 256 * c] = __uint_as_float((unsigned)v[c]);
            const int timeout = (++spn > 2000000u);   // fail, don't hang
            ok = __syncthreads_and((int)all | timeout | (int)dead);
        } while (!ok);
        if (spn > 2000000u) dead = true;

        // h_{t-1} slice (no trailing barrier needed: svh[p] is only rewritten
        // at step t+2, gated by step t+1's rendezvous barrier)
        const float4 s2 = *(const float4*)&svh[p][kb];
        const float4 s3 = *(const float4*)&svh[p][kb + 256];
        const float4 s4 = *(const float4*)&svh[p][kb + 512];
        const float4 s5 = *(const float4*)&svh[p][kb + 768];

        if (t < T_STEPS) {
            // ---- gates GEMV: 4 rows, weights + h in regs ----
            float acc[4];
            #pragma unroll
            for (int q = 0; q < 4; ++q) {
                acc[q] = w[q][0].x*x0.x + w[q][0].y*x0.y + w[q][0].z*x0.z + w[q][0].w*x0.w
                       + w[q][1].x*x1.x + w[q][1].y*x1.y + w[q][1].z*x1.z + w[q][1].w*x1.w
                       + w[q][2].x*s2.x + w[q][2].y*s2.y + w[q][2].z*s2.z + w[q][2].w*s2.w
                       + w[q][3].x*s3.x + w[q][3].y*s3.y + w[q][3].z*s3.z + w[q][3].w*s3.w
                       + w[q][4].x*s4.x + w[q][4].y*s4.y + w[q][4].z*s4.z + w[q][4].w*s4.w
                       + w[q][5].x*s5.x + w[q][5].y*s5.y + w[q][5].z*s5.z + w[q][5].w*s5.w;
            }
            #pragma unroll
            for (int q = 0; q < 4; ++q) {
                float s = acc[q];
                #pragma unroll
                for (int off = 32; off; off >>= 1) s += __shfl_xor(s, off);
                acc[q] = s;
            }
            const float iv = sigmoidf_(acc[0] + bias[0]);
            const float fv = sigmoidf_(acc[1] + bias[1]);
            const float gv = tanhf   (acc[2] + bias[2]);
            const float ov = sigmoidf_(acc[3] + bias[3]);
            c_state = fv * c_state + iv * gv;
            const float h = ov * tanhf(c_state);
            if (lane == 0) {  // publish FIRST: critical path
                __hip_atomic_store(&bufp[(size_t)(p ^ 1) * HID + j],
                    ((ull)(unsigned)(t + 2) << 32) | (ull)__float_as_uint(h),
                    __ATOMIC_RELAXED, __HIP_MEMORY_SCOPE_AGENT);
            }
        }

        // ---- fused dense: logits[t-1] rows {wg*2, wg*2+1} (off critical path) ----
        if (t > 0 && wv < 2) {
            float d = wd[0].x*s2.x + wd[0].y*s2.y + wd[0].z*s2.z + wd[0].w*s2.w
                    + wd[1].x*s3.x + wd[1].y*s3.y + wd[1].z*s3.z + wd[1].w*s3.w
                    + wd[2].x*s4.x + wd[2].y*s4.y + wd[2].z*s4.z + wd[2].w*s4.w
                    + wd[3].x*s5.x + wd[3].y*s5.y + wd[3].z*s5.z + wd[3].w*s5.w;
            #pragma unroll
            for (int off = 32; off; off >>= 1) d += __shfl_xor(d, off);
            if (lane == 0)
                logits[(size_t)(t - 1) * NC + drow] = d + dbias;
        }
    }
}

// ---------------- Kernel 2: P[t] = softmax_C(logits[t]) ----------------
// 2048 blocks x 256 thr; wave handles 2 rows; lane reads 8 contiguous floats.
__global__ __launch_bounds__(256) void softmaxC_k(
    const float* __restrict__ logits, float* __restrict__ P)
{
    const int tid = threadIdx.x;
    const int lane = tid & 63, wvv = tid >> 6;
    #pragma unroll
    for (int rr = 0; rr < 2; ++rr) {
        const int row = blockIdx.x * 8 + wvv * 2 + rr;
        const float4 a = *(const float4*)&logits[(size_t)row * NC + lane * 8];
        const float4 b = *(const float4*)&logits[(size_t)row * NC + lane * 8 + 4];
        float m = fmaxf(fmaxf(fmaxf(a.x, a.y), fmaxf(a.z, a.w)),
                        fmaxf(fmaxf(b.x, b.y), fmaxf(b.z, b.w)));
        #pragma unroll
        for (int off = 32; off; off >>= 1) m = fmaxf(m, __shfl_xor(m, off));
        float4 ea, eb;
        ea.x = expf(a.x - m); ea.y = expf(a.y - m); ea.z = expf(a.z - m); ea.w = expf(a.w - m);
        eb.x = expf(b.x - m); eb.y = expf(b.y - m); eb.z = expf(b.z - m); eb.w = expf(b.w - m);
        float s = ea.x + ea.y + ea.z + ea.w + eb.x + eb.y + eb.z + eb.w;
        #pragma unroll
        for (int off = 32; off; off >>= 1) s += __shfl_xor(s, off);
        const float inv = 1.f / s;
        ea.x *= inv; ea.y *= inv; ea.z *= inv; ea.w *= inv;
        eb.x *= inv; eb.y *= inv; eb.z *= inv; eb.w *= inv;
        *(float4*)&P[(size_t)row * NC + lane * 8]     = ea;
        *(float4*)&P[(size_t)row * NC + lane * 8 + 4] = eb;
    }
}

// ---------------- Kernel 3a: colsum[c] = sum_t exp(P[t][c]) ----------------
__global__ __launch_bounds__(256) void colsum_k(const float* __restrict__ P, float* __restrict__ cs)
{
    const int tid = threadIdx.x;
    const int c  = blockIdx.x * 16 + (tid & 15);
    const int tr = tid >> 4;
    float s = 0.f;
    #pragma unroll 8
    for (int t = tr; t < T_STEPS; t += 16) s += expf(P[(size_t)t * NC + c]);
    __shared__ float red[256];
    red[tid] = s; __syncthreads();
    for (int off = 128; off >= 16; off >>= 1) {
        if (tid < off) red[tid] += red[tid + off];
        __syncthreads();
    }
    if (tid < 16) cs[blockIdx.x * 16 + tid] = red[tid];
}

// ---------------- Kernel 3b: out = exp(P) / colsum ----------------
__global__ __launch_bounds__(256) void norm_k(float* P, const float* __restrict__ cs)
{
    size_t i = (size_t)blockIdx.x * 256 + threadIdx.x;
    const size_t n = (size_t)T_STEPS * NC;
    const size_t stride = (size_t)gridDim.x * 256;
    for (; i < n; i += stride) P[i] = expf(P[i]) / cs[i & (NC - 1)];
}

extern "C" void kernel_launch(void* const* d_in, const int* in_sizes, int n_in,
                              void* d_out, int out_size, void* d_ws, size_t ws_size,
                              hipStream_t stream) {
    const float* X    = (const float*)d_in[0];
    const float* h0   = (const float*)d_in[1];
    const float* c0   = (const float*)d_in[2];
    const float* W_ih = (const float*)d_in[3];
    const float* W_hh = (const float*)d_in[4];
    const float* b_ih = (const float*)d_in[5];
    const float* b_hh = (const float*)d_in[6];
    const float* Wd   = (const float*)d_in[7];
    const float* bd   = (const float*)d_in[8];
    float* out = (float*)d_out;

    char* ws = (char*)d_ws;
    ull*   bufp   = (ull*)ws;                    // [2][HID] epoch|h (16 KB)
    float* cs     = (float*)(ws + 16384);        // [NC]
    float* logits = (float*)(ws + 32768);        // [T, NC] (33.5 MB)

    init_k<<<1, HID, 0, stream>>>(h0, bufp);
    lstm_rec<<<NWG, TPB, 0, stream>>>(X, c0, W_ih, W_hh, b_ih, b_hh, Wd, bd, logits, bufp);
    softmaxC_k<<<T_STEPS / 8, 256, 0, stream>>>(logits, out);
    colsum_k<<<NC / 16, 256, 0, stream>>>(out, cs);
    norm_k<<<2048, 256, 0, stream>>>(out, cs);
}